// Round 5
// baseline (240.515 us; speedup 1.0000x reference)
//
#include <hip/hip_runtime.h>
#include <hip/hip_bf16.h>
#include <math.h>

#define NTOK 1600
#define CDIM 256
#define DK   64

typedef __attribute__((ext_vector_type(8))) short bf16x8;
typedef __attribute__((ext_vector_type(4))) float f32x4;

__device__ inline unsigned short f2bf(float v) {
    unsigned int u = __float_as_uint(v);
    unsigned int r = (u + 0x7fffu + ((u >> 16) & 1u)) >> 16;
    return (unsigned short)r;
}

// ---------------------------------------------------------------------------
// Kernel A: geometric relation table, wave-per-idx (1600 waves, 400 blocks).
// ---------------------------------------------------------------------------
__global__ __launch_bounds__(256) void geo_table_kernel(
    const float* __restrict__ W1, const float* __restrict__ b1,
    const float* __restrict__ W2, const float* __restrict__ b2,
    const float* __restrict__ Wgr, const float* __restrict__ bgr,
    float* __restrict__ table)
{
    __shared__ float e1s[4][64];
    __shared__ float e2s[4][64];
    int t = threadIdx.x;
    int w = t >> 6, j = t & 63;
    int idx = blockIdx.x * 4 + w;
    int ady = idx / 40, adx = idx % 40;
    float g0 = logf((float)adx + 1e-8f);
    float g1 = logf((float)ady + 1e-8f);
    float gc = logf(1e-8f);

    float e1 = fmaxf(g0*W1[j] + g1*W1[64+j] + gc*(W1[128+j]+W1[192+j]) + b1[j], 0.f);
    e1s[w][j] = e1;
    __syncthreads();

    float e2 = b2[j];
    #pragma unroll 8
    for (int i = 0; i < 64; ++i) e2 += e1s[w][i] * W2[i*64 + j];
    e2 = fmaxf(e2, 0.f);
    e2s[w][j] = e2;
    __syncthreads();

    int r = j & 15, q = j >> 4;
    float v = (q == 0) ? bgr[r] : 0.f;
    #pragma unroll
    for (int i = 0; i < 16; ++i) v += e2s[w][q*16 + i] * Wgr[(q*16 + i)*16 + r];
    v += __shfl_xor(v, 16); v += __shfl_xor(v, 32);
    v = fmaxf(v, 0.f);
    v += __shfl_xor(v, 1); v += __shfl_xor(v, 2);
    v += __shfl_xor(v, 4); v += __shfl_xor(v, 8);
    if (j == 0) table[idx] = v * (1.f / 16.f);
}

// ---------------------------------------------------------------------------
// Kernel B: QKV projection via bf16 MFMA; Vt store now block-wide coalesced.
// grid (25 ntiles, 6 jt, 4 b), 256 thr = 4 waves.
// ---------------------------------------------------------------------------
__global__ __launch_bounds__(256) void qkv_kernel(
    const float* __restrict__ x,
    const float* __restrict__ Wq, const float* __restrict__ bq,
    const float* __restrict__ Wk, const float* __restrict__ bk,
    const float* __restrict__ Wv, const float* __restrict__ bv,
    unsigned short* __restrict__ Qb, unsigned short* __restrict__ Kb,
    unsigned short* __restrict__ Vt)
{
    const int N = NTOK;
    int bx = blockIdx.x, jt = blockIdx.y, b = blockIdx.z;
    const float* Wm; const float* bias; int jb, stride;
    if (jt == 0)      { Wm = Wq; bias = bq; jb = 0;         stride = 64;  }
    else if (jt == 1) { Wm = Wk; bias = bk; jb = 0;         stride = 64;  }
    else              { Wm = Wv; bias = bv; jb = (jt-2)*64; stride = 256; }

    __shared__ __align__(16) unsigned short As[64*72];   // [n][k] pad 72
    __shared__ __align__(16) unsigned short Bs[64*72];   // [j][k] pad 72

    int t = threadIdx.x;
    int w = t >> 6, l = t & 63;
    int l15 = l & 15, l4 = l >> 4;
    int n0 = bx * 64;

    f32x4 acc[4];
    #pragma unroll
    for (int i = 0; i < 4; ++i) acc[i] = (f32x4){0.f,0.f,0.f,0.f};

    for (int kc = 0; kc < 4; ++kc) {
        int k0 = kc * 64;
        __syncthreads();
        #pragma unroll
        for (int p = 0; p < 4; ++p) {
            int k = p*16 + (t >> 4);
            int n4 = (t & 15) * 4;
            float4 xv = *(const float4*)&x[((size_t)(b*CDIM) + k0 + k)*N + n0 + n4];
            As[(n4+0)*72 + k] = f2bf(xv.x); As[(n4+1)*72 + k] = f2bf(xv.y);
            As[(n4+2)*72 + k] = f2bf(xv.z); As[(n4+3)*72 + k] = f2bf(xv.w);
            float4 wv = *(const float4*)&Wm[(size_t)(k0 + k)*stride + jb + n4];
            Bs[(n4+0)*72 + k] = f2bf(wv.x); Bs[(n4+1)*72 + k] = f2bf(wv.y);
            Bs[(n4+2)*72 + k] = f2bf(wv.z); Bs[(n4+3)*72 + k] = f2bf(wv.w);
        }
        __syncthreads();
        #pragma unroll
        for (int ks = 0; ks < 2; ++ks) {
            bf16x8 a = *(const bf16x8*)&As[(w*16 + l15)*72 + ks*32 + l4*8];
            #pragma unroll
            for (int jt4 = 0; jt4 < 4; ++jt4) {
                bf16x8 bf = *(const bf16x8*)&Bs[(jt4*16 + l15)*72 + ks*32 + l4*8];
                acc[jt4] = __builtin_amdgcn_mfma_f32_16x16x32_bf16(a, bf, acc[jt4], 0, 0, 0);
            }
        }
    }

    if (jt <= 1) {
        unsigned short* outb = (jt == 0 ? Qb : Kb) + (size_t)b*N*DK;
        float scale = (jt == 0) ? 0.125f : 1.0f;
        #pragma unroll
        for (int jt4 = 0; jt4 < 4; ++jt4) {
            int j = jt4*16 + l15;
            float bb = bias[j];
            #pragma unroll
            for (int r = 0; r < 4; ++r) {
                int n = n0 + w*16 + l4*4 + r;
                outb[(size_t)n*DK + j] = f2bf((acc[jt4][r] + bb) * scale);
            }
        }
    } else {
        __syncthreads();
        // stage full 64c x 64n bf16 tile in As (stride 68)
        unsigned short* sv = As;
        #pragma unroll
        for (int jt4 = 0; jt4 < 4; ++jt4) {
            int j = jt4*16 + l15;
            float bb = bias[jb + j];
            #pragma unroll
            for (int r = 0; r < 4; ++r)
                sv[j*68 + w*16 + l4*4 + r] = f2bf(acc[jt4][r] + bb);
        }
        __syncthreads();
        // coalesced store: 8 lanes x 16B = one 128B row per c
        #pragma unroll
        for (int p = 0; p < 2; ++p) {
            int c   = p*32 + (t >> 3);
            int off = (t & 7) * 8;
            uint4 v = *(const uint4*)&sv[c*68 + off];
            *(uint4*)&Vt[((size_t)b*CDIM + jb + c)*N + n0 + off] = v;
        }
    }
}

// ---------------------------------------------------------------------------
// Kernel C: MFMA attention. 512 threads = 8 waves, no main-loop barriers.
// 50 work units of 32 keys; wave w takes units u = w, w+8, ...
// Private per-wave LDS P tile; combine partials via LDS atomics at end.
// grid (100 ntiles, 4 b).
// ---------------------------------------------------------------------------
__global__ __launch_bounds__(512) void attn_kernel(
    const float* __restrict__ x, const float* __restrict__ gtab,
    const unsigned short* __restrict__ Qb, const unsigned short* __restrict__ Kb,
    const unsigned short* __restrict__ Vt, float* __restrict__ out)
{
    const int N = NTOK, C = CDIM;
    int b = blockIdx.y, n0 = blockIdx.x * 16;
    int t = threadIdx.x;
    int w = t >> 6, l = t & 63;
    int l15 = l & 15, l4 = l >> 4;

    __shared__ __align__(16) unsigned short Pl[8][16*40];  // per-wave P tiles
    __shared__ float sh_g[NTOK];
    __shared__ float outs[16][260];
    __shared__ float zs[16];

    for (int p = t; p < NTOK;   p += 512) sh_g[p] = gtab[p];
    for (int p = t; p < 16*260; p += 512) ((float*)outs)[p] = 0.f;
    if (t < 16) zs[t] = 0.f;

    const unsigned short* qrow = &Qb[((size_t)b*N + n0 + l15)*DK + l4*8];
    bf16x8 qa0 = *(const bf16x8*)qrow;
    bf16x8 qa1 = *(const bf16x8*)(qrow + 32);

    f32x4 acc[16];
    #pragma unroll
    for (int i = 0; i < 16; ++i) acc[i] = (f32x4){0.f,0.f,0.f,0.f};
    float z[4] = {0.f, 0.f, 0.f, 0.f};

    int yn[4], xn[4];
    #pragma unroll
    for (int r = 0; r < 4; ++r) {
        int n = n0 + l4*4 + r;
        yn[r] = n / 40; xn[r] = n - 40*yn[r];
    }

    __syncthreads();

    unsigned short* Pw = &Pl[w][0];

    for (int u = w; u < 50; u += 8) {
        int m0 = u * 32;
        // ---- S phase: 2 key sub-tiles of 16 ----
        #pragma unroll
        for (int tt = 0; tt < 2; ++tt) {
            int mg = m0 + tt*16 + l15;
            const unsigned short* kbase = &Kb[((size_t)b*N + mg)*DK + l4*8];
            bf16x8 kb0 = *(const bf16x8*)kbase;
            bf16x8 kb1 = *(const bf16x8*)(kbase + 32);
            f32x4 s4 = (f32x4){0.f,0.f,0.f,0.f};
            s4 = __builtin_amdgcn_mfma_f32_16x16x32_bf16(qa0, kb0, s4, 0, 0, 0);
            s4 = __builtin_amdgcn_mfma_f32_16x16x32_bf16(qa1, kb1, s4, 0, 0, 0);
            int ym = mg / 40, xm = mg - 40*ym;
            #pragma unroll
            for (int r = 0; r < 4; ++r) {
                float e = __expf(s4[r]);
                z[r] += e;
                int ady = ym - yn[r]; ady = ady < 0 ? -ady : ady;
                int adx = xm - xn[r]; adx = adx < 0 ? -adx : adx;
                Pw[(l4*4 + r)*40 + tt*16 + l15] = f2bf(e * sh_g[ady*40 + adx]);
            }
        }
        // ---- PV phase: 16 c-tiles, K=32 ----
        bf16x8 pa = *(const bf16x8*)&Pw[l15*40 + l4*8];
        #pragma unroll
        for (int ct = 0; ct < 16; ++ct) {
            const unsigned short* vb = &Vt[((size_t)b*C + ct*16 + l15)*N + m0 + l4*8];
            bf16x8 v0 = *(const bf16x8*)vb;
            acc[ct] = __builtin_amdgcn_mfma_f32_16x16x32_bf16(pa, v0, acc[ct], 0, 0, 0);
        }
    }

    // ---- combine partials across waves ----
    #pragma unroll
    for (int r = 0; r < 4; ++r) {
        float v = z[r];
        v += __shfl_xor(v, 1); v += __shfl_xor(v, 2);
        v += __shfl_xor(v, 4); v += __shfl_xor(v, 8);
        if (l15 == 0) atomicAdd(&zs[l4*4 + r], v);
    }
    #pragma unroll
    for (int ct = 0; ct < 16; ++ct)
        #pragma unroll
        for (int r = 0; r < 4; ++r)
            atomicAdd(&outs[l4*4 + r][ct*16 + l15], acc[ct][r]);
    __syncthreads();

    // ---- epilogue: normalize + residual, coalesced along n ----
    int r2 = t & 15;
    int cg = t >> 4;            // 0..31
    float invz = 1.f / zs[r2];
    #pragma unroll
    for (int p = 0; p < 8; ++p) {
        int c2 = p*32 + cg;
        size_t gi = ((size_t)b*C + c2)*N + n0 + r2;
        out[gi] = x[gi] + outs[r2][c2] * invz;
    }
}

// ---------------------------------------------------------------------------
extern "C" void kernel_launch(void* const* d_in, const int* in_sizes, int n_in,
                              void* d_out, int out_size, void* d_ws, size_t ws_size,
                              hipStream_t stream)
{
    const float* x   = (const float*)d_in[0];
    const float* Wq  = (const float*)d_in[1];
    const float* bq  = (const float*)d_in[2];
    const float* Wk  = (const float*)d_in[3];
    const float* bk  = (const float*)d_in[4];
    const float* Wv  = (const float*)d_in[5];
    const float* bv  = (const float*)d_in[6];
    const float* Wg1 = (const float*)d_in[7];
    const float* bg1 = (const float*)d_in[8];
    const float* Wg2 = (const float*)d_in[9];
    const float* bg2 = (const float*)d_in[10];
    const float* Wgr = (const float*)d_in[11];
    const float* bgr = (const float*)d_in[12];

    char* ws = (char*)d_ws;
    float* table       = (float*)ws;                              // 6400 B
    unsigned short* Qb = (unsigned short*)(ws + 8192);            // 819200 B
    unsigned short* Kb = (unsigned short*)(ws + 8192 + 819200);
    unsigned short* Vt = (unsigned short*)(ws + 8192 + 2*819200); // 3276800 B

    geo_table_kernel<<<dim3(400), dim3(256), 0, stream>>>(Wg1, bg1, Wg2, bg2, Wgr, bgr, table);
    qkv_kernel<<<dim3(25, 6, 4), dim3(256), 0, stream>>>(x, Wq, bq, Wk, bk, Wv, bv, Qb, Kb, Vt);
    attn_kernel<<<dim3(100, 4), dim3(512), 0, stream>>>(x, table, Qb, Kb, Vt, (float*)d_out);
}

// Round 6
// 184.580 us; speedup vs baseline: 1.3030x; 1.3030x over previous
//
#include <hip/hip_runtime.h>
#include <hip/hip_bf16.h>
#include <math.h>

#define NTOK 1600
#define CDIM 256
#define DK   64

typedef __attribute__((ext_vector_type(8))) short bf16x8;
typedef __attribute__((ext_vector_type(4))) float f32x4;

__device__ inline unsigned short f2bf(float v) {
    unsigned int u = __float_as_uint(v);
    unsigned int r = (u + 0x7fffu + ((u >> 16) & 1u)) >> 16;
    return (unsigned short)r;
}

// ---------------------------------------------------------------------------
// Kernel A: geometric relation table, wave-per-idx (1600 waves, 400 blocks).
// ---------------------------------------------------------------------------
__global__ __launch_bounds__(256) void geo_table_kernel(
    const float* __restrict__ W1, const float* __restrict__ b1,
    const float* __restrict__ W2, const float* __restrict__ b2,
    const float* __restrict__ Wgr, const float* __restrict__ bgr,
    float* __restrict__ table)
{
    __shared__ float e1s[4][64];
    __shared__ float e2s[4][64];
    int t = threadIdx.x;
    int w = t >> 6, j = t & 63;
    int idx = blockIdx.x * 4 + w;
    int ady = idx / 40, adx = idx % 40;
    float g0 = logf((float)adx + 1e-8f);
    float g1 = logf((float)ady + 1e-8f);
    float gc = logf(1e-8f);

    float e1 = fmaxf(g0*W1[j] + g1*W1[64+j] + gc*(W1[128+j]+W1[192+j]) + b1[j], 0.f);
    e1s[w][j] = e1;
    __syncthreads();

    float e2 = b2[j];
    #pragma unroll 8
    for (int i = 0; i < 64; ++i) e2 += e1s[w][i] * W2[i*64 + j];
    e2 = fmaxf(e2, 0.f);
    e2s[w][j] = e2;
    __syncthreads();

    int r = j & 15, q = j >> 4;
    float v = (q == 0) ? bgr[r] : 0.f;
    #pragma unroll
    for (int i = 0; i < 16; ++i) v += e2s[w][q*16 + i] * Wgr[(q*16 + i)*16 + r];
    v += __shfl_xor(v, 16); v += __shfl_xor(v, 32);
    v = fmaxf(v, 0.f);
    v += __shfl_xor(v, 1); v += __shfl_xor(v, 2);
    v += __shfl_xor(v, 4); v += __shfl_xor(v, 8);
    if (j == 0) table[idx] = v * (1.f / 16.f);
}

// ---------------------------------------------------------------------------
// Kernel B: QKV projection via bf16 MFMA. 512 thr = 8 waves:
// wave w -> n-panel (w>>1, 16 rows) x j-half (w&1, 32 cols). acc[2].
// grid (25 ntiles, 6 jt, 4 b).
// ---------------------------------------------------------------------------
__global__ __launch_bounds__(512) void qkv_kernel(
    const float* __restrict__ x,
    const float* __restrict__ Wq, const float* __restrict__ bq,
    const float* __restrict__ Wk, const float* __restrict__ bk,
    const float* __restrict__ Wv, const float* __restrict__ bv,
    unsigned short* __restrict__ Qb, unsigned short* __restrict__ Kb,
    unsigned short* __restrict__ Vt)
{
    const int N = NTOK;
    int bx = blockIdx.x, jt = blockIdx.y, b = blockIdx.z;
    const float* Wm; const float* bias; int jb, stride;
    if (jt == 0)      { Wm = Wq; bias = bq; jb = 0;         stride = 64;  }
    else if (jt == 1) { Wm = Wk; bias = bk; jb = 0;         stride = 64;  }
    else              { Wm = Wv; bias = bv; jb = (jt-2)*64; stride = 256; }

    __shared__ __align__(16) unsigned short As[64*72];   // [n][k] pad 72
    __shared__ __align__(16) unsigned short Bs[64*72];   // [j][k] pad 72

    int t = threadIdx.x;
    int w = t >> 6, l = t & 63;
    int l15 = l & 15, l4 = l >> 4;
    int panel = w >> 1;          // n-panel 0..3
    int jhalf = w & 1;           // j-half 0..1
    int n0 = bx * 64;

    f32x4 acc[2];
    acc[0] = (f32x4){0.f,0.f,0.f,0.f};
    acc[1] = (f32x4){0.f,0.f,0.f,0.f};

    for (int kc = 0; kc < 4; ++kc) {
        int k0 = kc * 64;
        __syncthreads();
        #pragma unroll
        for (int p = 0; p < 2; ++p) {
            int idx = p*512 + t;
            int k = idx >> 4, n4 = (idx & 15) * 4;
            float4 xv = *(const float4*)&x[((size_t)(b*CDIM) + k0 + k)*N + n0 + n4];
            As[(n4+0)*72 + k] = f2bf(xv.x); As[(n4+1)*72 + k] = f2bf(xv.y);
            As[(n4+2)*72 + k] = f2bf(xv.z); As[(n4+3)*72 + k] = f2bf(xv.w);
            float4 wv = *(const float4*)&Wm[(size_t)(k0 + k)*stride + jb + n4];
            Bs[(n4+0)*72 + k] = f2bf(wv.x); Bs[(n4+1)*72 + k] = f2bf(wv.y);
            Bs[(n4+2)*72 + k] = f2bf(wv.z); Bs[(n4+3)*72 + k] = f2bf(wv.w);
        }
        __syncthreads();
        #pragma unroll
        for (int ks = 0; ks < 2; ++ks) {
            bf16x8 a = *(const bf16x8*)&As[(panel*16 + l15)*72 + ks*32 + l4*8];
            #pragma unroll
            for (int jj = 0; jj < 2; ++jj) {
                bf16x8 bf = *(const bf16x8*)&Bs[(jhalf*32 + jj*16 + l15)*72 + ks*32 + l4*8];
                acc[jj] = __builtin_amdgcn_mfma_f32_16x16x32_bf16(a, bf, acc[jj], 0, 0, 0);
            }
        }
    }

    if (jt <= 1) {
        unsigned short* outb = (jt == 0 ? Qb : Kb) + (size_t)b*N*DK;
        float scale = (jt == 0) ? 0.125f : 1.0f;
        #pragma unroll
        for (int jj = 0; jj < 2; ++jj) {
            int j = jhalf*32 + jj*16 + l15;
            float bb = bias[j];
            #pragma unroll
            for (int r = 0; r < 4; ++r) {
                int n = n0 + panel*16 + l4*4 + r;
                outb[(size_t)n*DK + j] = f2bf((acc[jj][r] + bb) * scale);
            }
        }
    } else {
        __syncthreads();
        // stage full 64c x 64n bf16 tile in As (stride 72)
        unsigned short* sv = As;
        #pragma unroll
        for (int jj = 0; jj < 2; ++jj) {
            int j = jhalf*32 + jj*16 + l15;
            float bb = bias[jb + j];
            #pragma unroll
            for (int r = 0; r < 4; ++r)
                sv[j*72 + panel*16 + l4*4 + r] = f2bf(acc[jj][r] + bb);
        }
        __syncthreads();
        // coalesced store: 8 lanes x 16B = one 128B row per c
        int c   = t >> 3;
        int off = (t & 7) * 8;
        uint4 v = *(const uint4*)&sv[c*72 + off];
        *(uint4*)&Vt[((size_t)b*CDIM + jb + c)*N + n0 + off] = v;
    }
}

// ---------------------------------------------------------------------------
// Kernel C: MFMA attention, c-split. Block = (16 q-rows, 64-c slice, b).
// Per 64-key chunk: wave w computes S[16][16] for key sub-tile w (2 MFMA),
// exp*geo -> shared P (dbuf, 1 barrier), then PV for its 16-c sub-tile of the
// block's 64-c slice (2 MFMA, acc[1]). Each block recomputes z (cheap) and
// writes out slice directly: no combine pass.
// grid (100 ntiles, 4 c-slices, 4 b) = 1600 blocks, 256 thr.
// ---------------------------------------------------------------------------
__global__ __launch_bounds__(256) void attn_kernel(
    const float* __restrict__ x, const float* __restrict__ gtab,
    const unsigned short* __restrict__ Qb, const unsigned short* __restrict__ Kb,
    const unsigned short* __restrict__ Vt, float* __restrict__ out)
{
    const int N = NTOK, C = CDIM;
    int b = blockIdx.z, c0 = blockIdx.y * 64, n0 = blockIdx.x * 16;
    int t = threadIdx.x;
    int w = t >> 6, l = t & 63;
    int l15 = l & 15, l4 = l >> 4;

    __shared__ __align__(16) unsigned short Pl[2][16*72];  // shared P, dbuf
    __shared__ float sh_g[NTOK];
    __shared__ float shZ[4][16];
    __shared__ float zsum[16];
    __shared__ __align__(16) float outs[64*17];            // [c-local][n-local]

    for (int p = t; p < NTOK; p += 256) sh_g[p] = gtab[p];

    const unsigned short* qrow = &Qb[((size_t)b*N + n0 + l15)*DK + l4*8];
    bf16x8 qa0 = *(const bf16x8*)qrow;
    bf16x8 qa1 = *(const bf16x8*)(qrow + 32);

    f32x4 acc = (f32x4){0.f,0.f,0.f,0.f};
    float z[4] = {0.f, 0.f, 0.f, 0.f};

    int yn[4], xn[4];
    #pragma unroll
    for (int r = 0; r < 4; ++r) {
        int n = n0 + l4*4 + r;
        yn[r] = n / 40; xn[r] = n - 40*yn[r];
    }
    int mcol = w*16 + l15;   // this wave's key column within each 64-chunk

    __syncthreads();

    for (int cc = 0; cc < 25; ++cc) {
        int m0 = cc * 64;
        // ---- S phase: this wave's 16-key sub-tile ----
        int mg = m0 + mcol;
        const unsigned short* kbase = &Kb[((size_t)b*N + mg)*DK + l4*8];
        bf16x8 kb0 = *(const bf16x8*)kbase;
        bf16x8 kb1 = *(const bf16x8*)(kbase + 32);
        f32x4 s4 = (f32x4){0.f,0.f,0.f,0.f};
        s4 = __builtin_amdgcn_mfma_f32_16x16x32_bf16(qa0, kb0, s4, 0, 0, 0);
        s4 = __builtin_amdgcn_mfma_f32_16x16x32_bf16(qa1, kb1, s4, 0, 0, 0);

        int ym = mg / 40, xm = mg - 40*ym;
        unsigned short* prow = &Pl[cc & 1][0];
        #pragma unroll
        for (int r = 0; r < 4; ++r) {
            float e = __expf(s4[r]);
            z[r] += e;
            int ady = ym - yn[r]; ady = ady < 0 ? -ady : ady;
            int adx = xm - xn[r]; adx = adx < 0 ? -adx : adx;
            prow[(l4*4 + r)*72 + mcol] = f2bf(e * sh_g[ady*40 + adx]);
        }
        __syncthreads();

        // ---- PV phase: this wave's 16-c sub-tile of the block's 64-c slice ----
        const unsigned short* pb = &Pl[cc & 1][l15*72 + l4*8];
        bf16x8 pa0 = *(const bf16x8*)pb;
        bf16x8 pa1 = *(const bf16x8*)(pb + 32);
        const unsigned short* vb = &Vt[((size_t)b*C + c0 + w*16 + l15)*N + m0 + l4*8];
        bf16x8 v0 = *(const bf16x8*)vb;
        bf16x8 v1 = *(const bf16x8*)(vb + 32);
        acc = __builtin_amdgcn_mfma_f32_16x16x32_bf16(pa0, v0, acc, 0, 0, 0);
        acc = __builtin_amdgcn_mfma_f32_16x16x32_bf16(pa1, v1, acc, 0, 0, 0);
        // P double-buffered: no trailing barrier
    }

    // ---- z reduce: over 16 key-columns, then across waves ----
    #pragma unroll
    for (int r = 0; r < 4; ++r) {
        float v = z[r];
        v += __shfl_xor(v, 1); v += __shfl_xor(v, 2);
        v += __shfl_xor(v, 4); v += __shfl_xor(v, 8);
        if (l15 == 0) shZ[w][l4*4 + r] = v;
    }
    // ---- stash acc to LDS for the transpose ----
    #pragma unroll
    for (int r = 0; r < 4; ++r)
        outs[(w*16 + l15)*17 + l4*4 + r] = acc[r];
    __syncthreads();

    if (t < 16) zsum[t] = 1.f / (shZ[0][t] + shZ[1][t] + shZ[2][t] + shZ[3][t]);
    __syncthreads();

    // ---- epilogue: normalize + residual, 64B-per-c-row stores ----
    int c  = t >> 2;            // 0..63
    int nl = (t & 3) * 4;       // 0,4,8,12
    size_t gi = ((size_t)b*C + c0 + c)*N + n0 + nl;
    float4 xv = *(const float4*)&x[gi];
    float4 o;
    o.x = xv.x + outs[c*17 + nl + 0] * zsum[nl + 0];
    o.y = xv.y + outs[c*17 + nl + 1] * zsum[nl + 1];
    o.z = xv.z + outs[c*17 + nl + 2] * zsum[nl + 2];
    o.w = xv.w + outs[c*17 + nl + 3] * zsum[nl + 3];
    *(float4*)&out[gi] = o;
}

// ---------------------------------------------------------------------------
extern "C" void kernel_launch(void* const* d_in, const int* in_sizes, int n_in,
                              void* d_out, int out_size, void* d_ws, size_t ws_size,
                              hipStream_t stream)
{
    const float* x   = (const float*)d_in[0];
    const float* Wq  = (const float*)d_in[1];
    const float* bq  = (const float*)d_in[2];
    const float* Wk  = (const float*)d_in[3];
    const float* bk  = (const float*)d_in[4];
    const float* Wv  = (const float*)d_in[5];
    const float* bv  = (const float*)d_in[6];
    const float* Wg1 = (const float*)d_in[7];
    const float* bg1 = (const float*)d_in[8];
    const float* Wg2 = (const float*)d_in[9];
    const float* bg2 = (const float*)d_in[10];
    const float* Wgr = (const float*)d_in[11];
    const float* bgr = (const float*)d_in[12];

    char* ws = (char*)d_ws;
    float* table       = (float*)ws;                              // 6400 B
    unsigned short* Qb = (unsigned short*)(ws + 8192);            // 819200 B
    unsigned short* Kb = (unsigned short*)(ws + 8192 + 819200);
    unsigned short* Vt = (unsigned short*)(ws + 8192 + 2*819200); // 3276800 B

    geo_table_kernel<<<dim3(400), dim3(256), 0, stream>>>(Wg1, bg1, Wg2, bg2, Wgr, bgr, table);
    qkv_kernel<<<dim3(25, 6, 4), dim3(512), 0, stream>>>(x, Wq, bq, Wk, bk, Wv, bv, Qb, Kb, Vt);
    attn_kernel<<<dim3(100, 4, 4), dim3(256), 0, stream>>>(x, table, Qb, Kb, Vt, (float*)d_out);
}